// Round 1
// 1124.011 us; speedup vs baseline: 1.1332x; 1.1332x over previous
//
#include <hip/hip_runtime.h>
#include <hip/hip_fp16.h>

// GCN_Embedding R9:
//  (a) k_part rewritten with LDS counting-sort staging: per 3125-edge sub-chunk,
//      hist -> exclusive scan -> rank-scatter into LDS -> bucket-ordered writeout.
//      Turns 16M isolated 8B scattered stores (64 lines/wave, ~12 cyc/lane
//      transaction-bound per rocprof: 24% HBM, 2% VALU) into ~51B contiguous
//      bucket runs (~10 transactions/wave).
//  (b) k_gacc/k_gfinal at 1024 threads/block: 16 -> 32 waves/CU (occupancy cap)
//      to hide the 16M random x[src] gather latency.

constexpr int N_NODES = 500000;
constexpr int N_EDGES = 16000000;
constexpr int F = 5;
constexpr int NPB = 1024;                        // nodes per bucket (dst >> 10)
constexpr int K_BKT = (N_NODES + NPB - 1) / NPB; // 489
constexpr int CAP = 35008;                       // edges per bucket slot
constexpr int PART_BLOCKS = 1024;
constexpr int CHUNK = N_EDGES / PART_BLOCKS;     // 15625 = 5^6
constexpr int SUB = 3125;                        // LDS-staged sub-chunk (5 rounds)

// ---------- init fixed bucket tails ----------
__global__ void k_init(unsigned* __restrict__ gtail) {
    int b = blockIdx.x * blockDim.x + threadIdx.x;
    if (b < K_BKT) gtail[b] = (unsigned)(b * CAP);
}

// ---------- partition: LDS counting-sort staging for coalesced writes ----------
__global__ __launch_bounds__(512) void k_part(const int* __restrict__ src,
                                              const int* __restrict__ dst,
                                              const float* __restrict__ ew,
                                              unsigned* __restrict__ gtail,
                                              uint2* __restrict__ sorted) {
    __shared__ uint2 stage[SUB];           // 25000 B staged payload
    __shared__ unsigned short sbkt[SUB];   // 6250 B bucket id per staged slot
    __shared__ unsigned hcnt[512];         // per-round bucket counts / rank ctrs
    __shared__ unsigned scn[512];          // scan workspace -> exclusive offsets
    __shared__ unsigned gb2[512];          // global_base - local_off per bucket
    const int t = threadIdx.x;
    const int base_e = blockIdx.x * CHUNK;

#pragma unroll 1
    for (int rnd = 0; rnd < CHUNK / SUB; ++rnd) {
        const int sub_lo = base_e + rnd * SUB;
        hcnt[t] = 0;
        __syncthreads();
        // 1) histogram (normal load: L3 serves the re-read below)
        for (int e = sub_lo + t; e < sub_lo + SUB; e += 512)
            atomicAdd(&hcnt[(unsigned)dst[e] >> 10], 1u);
        __syncthreads();
        // 2) Hillis-Steele inclusive scan over 512 entries (489 valid)
        scn[t] = hcnt[t];
        __syncthreads();
        for (int d = 1; d < 512; d <<= 1) {
            unsigned add = (t >= d) ? scn[t - d] : 0u;
            __syncthreads();
            scn[t] += add;
            __syncthreads();
        }
        // 3) exclusive offsets + global reservation folded into one base
        unsigned cnt = hcnt[t];
        scn[t] -= cnt; // exclusive scan (own-element, no race)
        if (t < K_BKT && cnt)
            gb2[t] = atomicAdd(&gtail[t], cnt) - scn[t]; // wraps ok (mod 2^32)
        __syncthreads();
        hcnt[t] = 0; // reuse as rank counters
        __syncthreads();
        // 4) rank-scatter payload into LDS (scattered, but LDS is cheap)
        for (int e = sub_lo + t; e < sub_lo + SUB; e += 512) {
            unsigned d = (unsigned)__builtin_nontemporal_load(dst + e);
            unsigned bkt = d >> 10;
            unsigned p = scn[bkt] + atomicAdd(&hcnt[bkt], 1u);
            uint2 pay;
            pay.x = (unsigned)__builtin_nontemporal_load(src + e) | ((d & (NPB - 1u)) << 19);
            pay.y = __float_as_uint(__builtin_nontemporal_load(ew + e));
            stage[p] = pay;
            sbkt[p] = (unsigned short)bkt;
        }
        __syncthreads();
        // 5) bucket-ordered writeout: consecutive p in a bucket -> consecutive
        //    global slots (avg run 6.4 edges = 51 B, wave spans ~10 buckets)
        for (int p = t; p < SUB; p += 512)
            sorted[gb2[sbkt[p]] + p] = stage[p];
        __syncthreads();
    }
}

// ---------- x = h @ W^T, 5 x f16 packed per node in one uint4 ----------
__device__ __forceinline__ uint4 pack5(const float o[F]) {
    __half2 p01 = __floats2half2_rn(o[0], o[1]);
    __half2 p23 = __floats2half2_rn(o[2], o[3]);
    __half2 p4z = __floats2half2_rn(o[4], 0.f);
    uint4 pk;
    pk.x = *(const unsigned*)&p01;
    pk.y = *(const unsigned*)&p23;
    pk.z = *(const unsigned*)&p4z;
    pk.w = 0u;
    return pk;
}

__global__ void k_lin(const float* __restrict__ h, const float* __restrict__ W,
                      uint4* __restrict__ x) {
    int i = blockIdx.x * blockDim.x + threadIdx.x;
    if (i >= N_NODES) return;
    float hv[F], o[F];
#pragma unroll
    for (int k = 0; k < F; ++k) hv[k] = h[i * F + k];
#pragma unroll
    for (int f = 0; f < F; ++f) {
        float acc = 0.f;
#pragma unroll
        for (int k = 0; k < F; ++k) acc = fmaf(hv[k], W[f * F + k], acc);
        o[f] = acc;
    }
    x[i] = pack5(o);
}

// ---------- per-edge accumulate: 3 x ds_pk_add_f16 ----------
__device__ __forceinline__ void edge_accum(unsigned long long pe,
                                           const uint4* __restrict__ x,
                                           __half2* __restrict__ acc) {
    unsigned px = (unsigned)pe;
    float w = __uint_as_float((unsigned)(pe >> 32));
    unsigned srci = px & 0x7FFFFu;
    unsigned dl = px >> 19;
    uint4 v = x[srci];
    float2 f01 = __half22float2(*reinterpret_cast<const __half2*>(&v.x));
    float2 f23 = __half22float2(*reinterpret_cast<const __half2*>(&v.y));
    float2 f4z = __half22float2(*reinterpret_cast<const __half2*>(&v.z));
    __half2* a = acc + dl * 3;
    unsafeAtomicAdd(a + 0, __floats2half2_rn(f01.x * w, f01.y * w));
    unsafeAtomicAdd(a + 1, __floats2half2_rn(f23.x * w, f23.y * w));
    unsafeAtomicAdd(a + 2, __floats2half2_rn(f4z.x * w, 1.0f));   // (f4, degree)
}

// ---------- per-bucket LDS accumulate + finish + next lin (1024 thr) ----------
__global__ __launch_bounds__(1024) void k_gacc(const unsigned long long* __restrict__ sorted,
                                               const unsigned* __restrict__ gtail,
                                               const uint4* __restrict__ x,
                                               const float* __restrict__ bias,
                                               const float* __restrict__ Wn,
                                               uint4* __restrict__ xn) {
    __shared__ __half2 acc[NPB * 3];
    for (int t = threadIdx.x; t < NPB * 3; t += 1024)
        acc[t] = __floats2half2_rn(0.f, 0.f);
    __syncthreads();
    unsigned lo = blockIdx.x * CAP, hi = gtail[blockIdx.x];
    unsigned e = lo + threadIdx.x;
    for (; e + 1024 < hi; e += 2048) {
        unsigned long long pe0 = __builtin_nontemporal_load(sorted + e);
        unsigned long long pe1 = __builtin_nontemporal_load(sorted + e + 1024);
        edge_accum(pe0, x, acc);
        edge_accum(pe1, x, acc);
    }
    if (e < hi) {
        unsigned long long pe0 = __builtin_nontemporal_load(sorted + e);
        edge_accum(pe0, x, acc);
    }
    __syncthreads();
    int li = threadIdx.x;
    int node = blockIdx.x * NPB + li;
    if (node < N_NODES) {
        const __half2* a = acc + li * 3;
        float2 s01 = __half22float2(a[0]);
        float2 s23 = __half22float2(a[1]);
        float2 s4c = __half22float2(a[2]);
        float inv = 1.0f / fmaxf(s4c.y, 1.0f);
        float sv[F] = {s01.x, s01.y, s23.x, s23.y, s4c.x};
        float hv[F], o[F];
#pragma unroll
        for (int f = 0; f < F; ++f) hv[f] = fmaxf(fmaf(sv[f], inv, bias[f]), 0.f);
#pragma unroll
        for (int f = 0; f < F; ++f) {
            float s = 0.f;
#pragma unroll
            for (int kk = 0; kk < F; ++kk) s = fmaf(hv[kk], Wn[f * F + kk], s);
            o[f] = s;
        }
        xn[node] = pack5(o);
    }
}

// ---------- last layer: accumulate + finish + full FC chain (f32 out) ----------
__global__ __launch_bounds__(1024) void k_gfinal(const unsigned long long* __restrict__ sorted,
                                                 const unsigned* __restrict__ gtail,
                                                 const uint4* __restrict__ x,
                                                 const float* __restrict__ b3,
                                                 const float* __restrict__ fcW1, const float* __restrict__ fcb1,
                                                 const float* __restrict__ fcW2, const float* __restrict__ fcb2,
                                                 const float* __restrict__ fcW3, const float* __restrict__ fcb3,
                                                 float* __restrict__ out) {
    __shared__ __half2 acc[NPB * 3];
    for (int t = threadIdx.x; t < NPB * 3; t += 1024)
        acc[t] = __floats2half2_rn(0.f, 0.f);
    __syncthreads();
    unsigned lo = blockIdx.x * CAP, hi = gtail[blockIdx.x];
    unsigned e = lo + threadIdx.x;
    for (; e + 1024 < hi; e += 2048) {
        unsigned long long pe0 = __builtin_nontemporal_load(sorted + e);
        unsigned long long pe1 = __builtin_nontemporal_load(sorted + e + 1024);
        edge_accum(pe0, x, acc);
        edge_accum(pe1, x, acc);
    }
    if (e < hi) {
        unsigned long long pe0 = __builtin_nontemporal_load(sorted + e);
        edge_accum(pe0, x, acc);
    }
    __syncthreads();
    int li = threadIdx.x;
    int node = blockIdx.x * NPB + li;
    if (node < N_NODES) {
        const __half2* a = acc + li * 3;
        float2 s01 = __half22float2(a[0]);
        float2 s23 = __half22float2(a[1]);
        float2 s4c = __half22float2(a[2]);
        float inv = 1.0f / fmaxf(s4c.y, 1.0f);
        float sv[F] = {s01.x, s01.y, s23.x, s23.y, s4c.x};
        float h3[F], t1[F], t2[F];
#pragma unroll
        for (int f = 0; f < F; ++f) h3[f] = fmaxf(fmaf(sv[f], inv, b3[f]), 0.f);
#pragma unroll
        for (int f = 0; f < F; ++f) {
            float s = fcb1[f];
#pragma unroll
            for (int kk = 0; kk < F; ++kk) s = fmaf(h3[kk], fcW1[f * F + kk], s);
            t1[f] = fmaxf(s, 0.f);
        }
#pragma unroll
        for (int f = 0; f < F; ++f) {
            float s = fcb2[f];
#pragma unroll
            for (int kk = 0; kk < F; ++kk) s = fmaf(t1[kk], fcW2[f * F + kk], s);
            t2[f] = fmaxf(s, 0.f);
        }
#pragma unroll
        for (int f = 0; f < F; ++f) {
            float s = fcb3[f];
#pragma unroll
            for (int kk = 0; kk < F; ++kk) s = fmaf(t2[kk], fcW3[f * F + kk], s);
            out[node * F + f] = s;
        }
    }
}

extern "C" void kernel_launch(void* const* d_in, const int* in_sizes, int n_in,
                              void* d_out, int out_size, void* d_ws, size_t ws_size,
                              hipStream_t stream) {
    const float* h    = (const float*)d_in[0];
    const int*   ei   = (const int*)d_in[1];
    const float* ew   = (const float*)d_in[2];
    const float* W1   = (const float*)d_in[3];
    const float* b1   = (const float*)d_in[4];
    const float* W2   = (const float*)d_in[5];
    const float* b2   = (const float*)d_in[6];
    const float* W3   = (const float*)d_in[7];
    const float* b3   = (const float*)d_in[8];
    const float* fcW1 = (const float*)d_in[9];
    const float* fcb1 = (const float*)d_in[10];
    const float* fcW2 = (const float*)d_in[11];
    const float* fcb2 = (const float*)d_in[12];
    const float* fcW3 = (const float*)d_in[13];
    const float* fcb3 = (const float*)d_in[14];
    float* out = (float*)d_out;

    const int* srcp = ei;
    const int* dstp = ei + N_EDGES;

    char* ws = (char*)d_ws;
    const size_t MiB = 1024 * 1024;
    unsigned* gtail   = (unsigned*)(ws + 0);           // 2 KB
    uint4*    xA      = (uint4*)(ws + 1 * MiB);        // 8 MB
    uint4*    xB      = (uint4*)(ws + 10 * MiB);       // 8 MB
    uint2*    sorted  = (uint2*)(ws + 19 * MiB);       // 489*35008*8 = 131 MiB
    const unsigned long long* sorted64 = (const unsigned long long*)sorted;

    dim3 gn((N_NODES + 255) / 256);

    // --- fixed-capacity bucket partition (once, reused by all 3 layers) ---
    k_init<<<1, 512, 0, stream>>>(gtail);
    k_part<<<PART_BLOCKS, 512, 0, stream>>>(srcp, dstp, ew, gtail, sorted);

    // --- layer pipeline ---
    k_lin<<<gn, 256, 0, stream>>>(h, W1, xA);
    k_gacc<<<K_BKT, 1024, 0, stream>>>(sorted64, gtail, xA, b1, W2, xB);
    k_gacc<<<K_BKT, 1024, 0, stream>>>(sorted64, gtail, xB, b2, W3, xA);
    k_gfinal<<<K_BKT, 1024, 0, stream>>>(sorted64, gtail, xA, b3,
                                         fcW1, fcb1, fcW2, fcb2, fcW3, fcb3, out);
}